// Round 1
// 735.452 us; speedup vs baseline: 1.0018x; 1.0018x over previous
//
#include <hip/hip_runtime.h>

// FeatureTexel: bilinear gather from 100000x16x9x9 fp32 atlas (518 MB > L3).
// Round 3: entry-major gather. The counting sort gives each atlas entry a
// contiguous segment of its samples; one WAVE per entry stages the whole
// 5184 B entry into LDS via coalesced float4 loads (a pure ascending sweep
// of the atlas => streaming HBM), then interpolates all its samples from
// LDS. Replaces the sample-major 4B-scattered gather (~2-4 KB effective
// fetch per sample) with compulsory-only traffic (~518 MB total).

constexpr int FD = 16;
constexpr int FS = 9;
constexpr int ENTRY_FLOATS = FD * FS * FS;    // 1296 floats = 5184 B
constexpr int ENTRY_F4     = ENTRY_FLOATS / 4; // 324 float4
constexpr int NSAMP = 65536 * 8;              // 524288 samples
constexpr int NUM_ATLAS = 100000;
constexpr int BLOCK = 256;
constexpr int WAVES_PER_BLOCK = 4;

constexpr int SCAN_CHUNK = 1024;                                   // elems per scan block
constexpr int NUM_SCAN_BLOCKS = (NUM_ATLAS + SCAN_CHUNK - 1) / SCAN_CHUNK;  // 98
constexpr int PARTIALS_PAD = 128;

// ws layout (ints): [hist NUM_ATLAS][partials PARTIALS_PAD][offsets NUM_ATLAS][order NSAMP]

__global__ __launch_bounds__(BLOCK) void hist_kernel(const int* __restrict__ inds,
                                                     int* __restrict__ hist) {
    int i = blockIdx.x * BLOCK + threadIdx.x;
    if (i < NSAMP) atomicAdd(&hist[inds[i]], 1);
}

__global__ __launch_bounds__(BLOCK) void scanA_kernel(const int* __restrict__ hist,
                                                      int* __restrict__ offsets,
                                                      int* __restrict__ partials) {
    __shared__ int lds[BLOCK];
    int t = threadIdx.x;
    int base = blockIdx.x * SCAN_CHUNK + t * 4;
    int v[4];
    #pragma unroll
    for (int j = 0; j < 4; ++j) v[j] = (base + j < NUM_ATLAS) ? hist[base + j] : 0;
    int sum = v[0] + v[1] + v[2] + v[3];
    lds[t] = sum;
    __syncthreads();
    // Hillis-Steele inclusive scan over 256 thread-sums
    for (int off = 1; off < BLOCK; off <<= 1) {
        int add = (t >= off) ? lds[t - off] : 0;
        __syncthreads();
        lds[t] += add;
        __syncthreads();
    }
    int incl = lds[t];
    int excl = incl - sum;
    if (t == BLOCK - 1) partials[blockIdx.x] = incl;
    int run = excl;
    #pragma unroll
    for (int j = 0; j < 4; ++j) {
        if (base + j < NUM_ATLAS) offsets[base + j] = run;
        run += v[j];
    }
}

// Parallel exclusive scan of the 98 block partials (was a serial 1-thread loop
// of dependent global round-trips).
__global__ __launch_bounds__(128) void scanB_kernel(int* __restrict__ partials) {
    __shared__ int lds[128];
    int t = threadIdx.x;
    int v = (t < NUM_SCAN_BLOCKS) ? partials[t] : 0;
    lds[t] = v;
    __syncthreads();
    for (int off = 1; off < 128; off <<= 1) {
        int add = (t >= off) ? lds[t - off] : 0;
        __syncthreads();
        lds[t] += add;
        __syncthreads();
    }
    if (t < NUM_SCAN_BLOCKS) partials[t] = lds[t] - v;   // exclusive
}

__global__ __launch_bounds__(BLOCK) void scanC_kernel(int* __restrict__ offsets,
                                                      const int* __restrict__ partials) {
    int i = blockIdx.x * BLOCK + threadIdx.x;
    if (i < NUM_ATLAS) offsets[i] += partials[i / SCAN_CHUNK];
}

__global__ __launch_bounds__(BLOCK) void scatter_kernel(const int* __restrict__ inds,
                                                        int* __restrict__ offsets,
                                                        int* __restrict__ order) {
    int i = blockIdx.x * BLOCK + threadIdx.x;
    if (i < NSAMP) {
        int ind = inds[i];
        int pos = atomicAdd(&offsets[ind], 1);   // offsets[e] ends at segment END
        order[pos] = i;
    }
}

// One wave per atlas entry. Stage entry e (contiguous 5184 B) into LDS with
// coalesced float4 loads, then interpolate its cnt samples: 16 lanes = 16
// channels per sample, 4 samples concurrently per wave.
__global__ __launch_bounds__(BLOCK) void gather_kernel(
    const float2* __restrict__ x,
    const float*  __restrict__ ft,
    const int*    __restrict__ order,
    const int*    __restrict__ hist,      // per-entry counts (intact after scans)
    const int*    __restrict__ seg_end,   // offsets[] after scatter = segment ends
    float*        __restrict__ out)
{
    __shared__ float4 tile[WAVES_PER_BLOCK][ENTRY_F4];   // 4 x 5184 B = 20736 B
    const int wv   = threadIdx.x >> 6;
    const int lane = threadIdx.x & 63;
    const int e    = blockIdx.x * WAVES_PER_BLOCK + wv;  // grid covers exactly NUM_ATLAS

    const int end   = seg_end[e];
    const int cnt   = hist[e];
    const int start = end - cnt;

    if (cnt > 0) {
        const float4* src = (const float4*)(ft + (size_t)e * ENTRY_FLOATS);
        #pragma unroll
        for (int k = 0; k < 5; ++k)
            tile[wv][lane + 64 * k] = src[lane + 64 * k];     // 320 float4
        if (lane < ENTRY_F4 - 320)                            // tail: 4 float4
            tile[wv][320 + lane] = src[320 + lane];
    }
    __syncthreads();   // drains vmcnt+lgkmcnt; each wave only reads its own tile

    if (cnt == 0) return;

    const float* L  = (const float*)tile[wv];
    const int ch    = lane & 15;    // channel
    const int sub   = lane >> 4;    // which of 4 concurrent samples
    const float fsm1 = (float)(FS - 1);

    for (int p = start + sub; p < end; p += 4) {
        int sid = order[p];          // broadcast across the 16-lane group
        float2 xy = x[sid];          // broadcast load

        float gx = fminf(fmaxf((xy.x + 1.0f) * 0.5f * fsm1, 0.0f), fsm1);
        float gy = fminf(fmaxf((xy.y + 1.0f) * 0.5f * fsm1, 0.0f), fsm1);
        int x0 = min((int)gx, FS - 2);   // gx>=0 so trunc == floor
        int y0 = min((int)gy, FS - 2);
        float wx = gx - (float)x0;
        float wy = gy - (float)y0;
        float w00 = (1.0f - wx) * (1.0f - wy);
        float w01 = wx * (1.0f - wy);
        float w10 = (1.0f - wx) * wy;
        float w11 = wx * wy;

        int base = ch * (FS * FS) + y0 * FS + x0;   // stride 81 (odd) across lanes -> conflict-light
        float r = L[base]          * w00 + L[base + 1]      * w01
                + L[base + FS]     * w10 + L[base + FS + 1] * w11;

        out[(size_t)sid * FD + ch] = r;   // 16 lanes -> one contiguous 64 B chunk
    }
}

extern "C" void kernel_launch(void* const* d_in, const int* in_sizes, int n_in,
                              void* d_out, int out_size, void* d_ws, size_t ws_size,
                              hipStream_t stream) {
    const float2* x    = (const float2*)d_in[0];
    const int*    inds = (const int*)d_in[1];
    const float*  ft   = (const float*)d_in[2];
    float*        out  = (float*)d_out;

    int* ws       = (int*)d_ws;
    int* hist     = ws;
    int* partials = hist + NUM_ATLAS;
    int* offsets  = partials + PARTIALS_PAD;
    int* order    = offsets + NUM_ATLAS;

    // zero hist only (partials fully written by scanA before scanB reads them)
    hipMemsetAsync(hist, 0, (size_t)NUM_ATLAS * sizeof(int), stream);

    hist_kernel<<<NSAMP / BLOCK, BLOCK, 0, stream>>>(inds, hist);
    scanA_kernel<<<NUM_SCAN_BLOCKS, BLOCK, 0, stream>>>(hist, offsets, partials);
    scanB_kernel<<<1, 128, 0, stream>>>(partials);
    scanC_kernel<<<(NUM_ATLAS + BLOCK - 1) / BLOCK, BLOCK, 0, stream>>>(offsets, partials);
    scatter_kernel<<<NSAMP / BLOCK, BLOCK, 0, stream>>>(inds, offsets, order);

    gather_kernel<<<NUM_ATLAS / WAVES_PER_BLOCK, BLOCK, 0, stream>>>(
        x, ft, order, hist, offsets, out);
}